// Round 1
// baseline (125.933 us; speedup 1.0000x reference)
//
#include <hip/hip_runtime.h>
#include <math.h>

#define NB   16
#define NH   128
#define NW   128
#define NCLS 80
#define NPOS (NB * NH * NW)          // 262144 spatial positions
#define STRIDE_F 8.0f

#define BLOCKS_A (NPOS / 256)        // 1024: bbox decode, 1 thread/pos
#define BLOCKS_B (NPOS / 64)         // 4096: cls reduce, 4 lanes/pos, 64 pos/block

typedef const __attribute__((address_space(1))) unsigned int ga_u32;
typedef __attribute__((address_space(3))) unsigned int lds_u32;

// Output layout (flat, reference return order):
//   [0 .. 4*NPOS)        xywh, float4 per position
//   [4*NPOS .. 5*NPOS)   argmax class index (as float)
//   [5*NPOS .. 6*NPOS)   conf = sqrt(sigmoid(center)*sigmoid(max_logit))
__global__ __launch_bounds__(256) void fcos_decode_kernel(
    const float* __restrict__ bbox,
    const float* __restrict__ center,
    const float* __restrict__ cls,
    float* __restrict__ out)
{
    // 4 waves * 16 positions * 320 B = 20480 B. 160 KiB/CU / 20 KiB -> 8 blocks/CU
    // = 32 waves/CU (max occupancy) — no occupancy loss from the staging buffer.
    __shared__ float lds[5120];

    const int bid = blockIdx.x;

    if (bid < BLOCKS_A) {
        // ---------- Role A: bbox ltrb->xywh, fully coalesced ----------
        const int pos = bid * 256 + threadIdx.x;
        const int w = pos & (NW - 1);
        const int h = (pos >> 7) & (NH - 1);

        const float4 ltrb = ((const float4*)bbox)[pos];
        const float l = expf(ltrb.x) * STRIDE_F;
        const float t = expf(ltrb.y) * STRIDE_F;
        const float r = expf(ltrb.z) * STRIDE_F;
        const float b = expf(ltrb.w) * STRIDE_F;

        const float cx = (float)w * STRIDE_F + STRIDE_F * 0.5f;
        const float cy = (float)h * STRIDE_F + STRIDE_F * 0.5f;

        ((float4*)out)[pos] = make_float4(cx - (l - r) * 0.5f,
                                          cy - (t - b) * 0.5f,
                                          l + r,
                                          t + b);
    } else {
        // ---------- Role B: class max/argmax + centerness conf ----------
        // Stage each wave's 16 positions (5120 contiguous bytes) into LDS via
        // global_load_lds: global side is instruction-level coalesced (16 lines
        // per load vs 64 for the old 80-B-strided register loads); LDS dest is
        // the required wave-uniform-base + lane*16 linear pattern.
        const int b    = bid - BLOCKS_A;
        const int wave = threadIdx.x >> 6;
        const int lane = threadIdx.x & 63;
        const int p    = lane >> 2;          // 0..15 position within wave
        const int q    = lane & 3;           // 0..3 class chunk
        const int pos  = b * 64 + wave * 16 + p;

        const char* gsrc = (const char*)cls + (size_t)(b * 64 + wave * 16) * (NCLS * 4);
        float* lbase = lds + wave * 1280;    // this wave's private 5120-B region

        #pragma unroll
        for (int k = 0; k < 5; ++k) {
            __builtin_amdgcn_global_load_lds(
                (ga_u32*)(gsrc + k * 1024 + (size_t)lane * 16),   // per-lane global src
                (lds_u32*)((char*)lbase + k * 1024),              // wave-uniform LDS base
                16, 0, 0);                                        // dwordx4 width
        }

        // Issue the center load now; the vmcnt(0) below covers it too.
        float cen = 0.0f;
        if (q == 0) cen = center[pos];

        // Per-wave private staging: no __syncthreads needed, just drain vmcnt.
        asm volatile("s_waitcnt vmcnt(0)" ::: "memory");

        // ds_read_b128 x5. Bank check: byte = 320p + 80q + 16k; start addresses
        // mod 128 cover all eight 16-B slots uniformly (8 lanes per 4-bank group,
        // distinct rows) -> structural-minimum 8 cyc per b128, i.e. conflict-free.
        const float4* lp = (const float4*)(lbase + p * 80 + q * 20);
        const float4 v0 = lp[0];
        const float4 v1 = lp[1];
        const float4 v2 = lp[2];
        const float4 v3 = lp[3];
        const float4 v4 = lp[4];

        float best = v0.x; int li = 0;
        #define SCAN(val, j) if ((val) > best) { best = (val); li = (j); }
        SCAN(v0.y, 1)  SCAN(v0.z, 2)  SCAN(v0.w, 3)
        SCAN(v1.x, 4)  SCAN(v1.y, 5)  SCAN(v1.z, 6)  SCAN(v1.w, 7)
        SCAN(v2.x, 8)  SCAN(v2.y, 9)  SCAN(v2.z, 10) SCAN(v2.w, 11)
        SCAN(v3.x, 12) SCAN(v3.y, 13) SCAN(v3.z, 14) SCAN(v3.w, 15)
        SCAN(v4.x, 16) SCAN(v4.y, 17) SCAN(v4.z, 18) SCAN(v4.w, 19)
        #undef SCAN
        int idx = q * 20 + li;

        // Butterfly over the 4-lane group; first-occurrence tie-break.
        #pragma unroll
        for (int mask = 1; mask <= 2; mask <<= 1) {
            const float ov = __shfl_xor(best, mask);
            const int   oi = __shfl_xor(idx,  mask);
            if (ov > best || (ov == best && oi < idx)) { best = ov; idx = oi; }
        }

        if (q == 0) {
            // 16 active lanes write 64 contiguous bytes each stream — coalesced.
            const float sc   = 1.0f / (1.0f + expf(-cen));
            const float ss   = 1.0f / (1.0f + expf(-best));
            out[(size_t)4 * NPOS + pos] = (float)idx;
            out[(size_t)5 * NPOS + pos] = sqrtf(sc * ss);
        }
    }
}

extern "C" void kernel_launch(void* const* d_in, const int* in_sizes, int n_in,
                              void* d_out, int out_size, void* d_ws, size_t ws_size,
                              hipStream_t stream)
{
    const float* bbox   = (const float*)d_in[0];
    const float* center = (const float*)d_in[1];
    const float* cls    = (const float*)d_in[2];
    float* out = (float*)d_out;

    fcos_decode_kernel<<<BLOCKS_A + BLOCKS_B, 256, 0, stream>>>(bbox, center, cls, out);
}